// Round 1
// baseline (512.584 us; speedup 1.0000x reference)
//
#include <hip/hip_runtime.h>
#include <hip/hip_bf16.h>

typedef __attribute__((ext_vector_type(4))) float  f32x4;
typedef __attribute__((ext_vector_type(8))) short  short8;

#define H_    1024
#define K_    2048   // 2H
#define B_    32
#define S_    1024
#define M_TOT 32768  // B*S

#define BM 128
#define BN 128
#define BK 64

static __device__ __forceinline__ unsigned short f2bf(float f) {
  __hip_bfloat16 h = __float2bfloat16(f);
  return __builtin_bit_cast(unsigned short, h);
}

// ---------------- prep: We [K][H] fp32 -> WeT [H][K] bf16 ----------------
__global__ void we_transpose_kernel(const float* __restrict__ We,
                                    unsigned short* __restrict__ WeT) {
  __shared__ float tile[32][33];
  int k0 = blockIdx.x * 32;
  int n0 = blockIdx.y * 32;
  int tx = threadIdx.x, ty = threadIdx.y;  // block (32,8)
#pragma unroll
  for (int i = 0; i < 32; i += 8)
    tile[ty + i][tx] = We[(size_t)(k0 + ty + i) * H_ + n0 + tx];
  __syncthreads();
#pragma unroll
  for (int i = 0; i < 32; i += 8)
    WeT[(size_t)(n0 + ty + i) * K_ + k0 + tx] = f2bf(tile[tx][ty + i]);
}

// ---------------- gamma_dec[b][h] = bd[h] + dec[b,:] @ Wd[:,h] ----------------
__global__ void gdec_kernel(const float* __restrict__ dec,
                            const float* __restrict__ Wd,
                            const float* __restrict__ bd,
                            float* __restrict__ gdec) {
  int h = blockIdx.x * 256 + threadIdx.x;
  int b = blockIdx.y;
  const float* dp = dec + b * H_;
  float acc = bd[h];
#pragma unroll 8
  for (int k = 0; k < H_; ++k) acc += dp[k] * Wd[(size_t)k * H_ + h];
  gdec[b * H_ + h] = acc;
}

// ---------------- fused GEMM + tanh + Wv-reduce -> partial scores ----------------
// grid (M_TOT/BM=256, H/BN=8), 256 threads (4 waves, 2x2 of 64x64 per wave)
__global__ __launch_bounds__(256)
void gemm_score_kernel(const float* __restrict__ ctx,
                       const unsigned short* __restrict__ WeT,
                       const float* __restrict__ be,
                       const float* __restrict__ gdec,
                       const float* __restrict__ Wv,
                       float* __restrict__ spart_g) {
  __shared__ __align__(16) unsigned short As[BM * BK];  // swizzled [row][k]
  __shared__ __align__(16) unsigned short Bs[BN * BK];  // swizzled [n][k]
  __shared__ float bg[BN];
  __shared__ float wvl[BN];
  __shared__ float sred[2][BM];

  const int tid  = threadIdx.x;
  const int lane = tid & 63;
  const int wid  = tid >> 6;
  const int wrow = wid >> 1, wcol = wid & 1;
  const int lc = lane & 15, l4 = lane >> 4;
  const int m0 = blockIdx.x * BM;
  const int n0 = blockIdx.y * BN;
  const int b  = m0 >> 10;  // S=1024, BM|S so one b per block

  if (tid < BN) {
    bg[tid]  = be[n0 + tid] + gdec[b * H_ + n0 + tid];
    wvl[tid] = Wv[n0 + tid];
  }

  // staging assignment: thread -> (row = tid>>1, half = tid&1) covers [128][64]
  const int srow  = tid >> 1;
  const int shalf = tid & 1;
  const float*          aptr = ctx + (size_t)(m0 + srow) * K_ + shalf * 32;
  const unsigned short* bptr = WeT + (size_t)(n0 + srow) * K_ + shalf * 32;
  const int swbase  = srow * 128;      // bytes per LDS row (64 bf16)
  const int schunk0 = shalf * 4;       // 16B-chunk index base within row
  const int srxor   = srow & 7;

  f32x4 acc[4][4];
#pragma unroll
  for (int mi = 0; mi < 4; ++mi)
#pragma unroll
    for (int ni = 0; ni < 4; ++ni) {
      f32x4 z = {0.f, 0.f, 0.f, 0.f};
      acc[mi][ni] = z;
    }

  for (int kt = 0; kt < K_ / BK; ++kt) {
    // ---- stage A: fp32 -> bf16, swizzled ds_write
    f32x4 f[8];
#pragma unroll
    for (int c = 0; c < 8; ++c)
      f[c] = *(const f32x4*)(aptr + kt * BK + c * 4);
#pragma unroll
    for (int c = 0; c < 4; ++c) {
      short8 v;
      v[0] = (short)f2bf(f[2 * c][0]);
      v[1] = (short)f2bf(f[2 * c][1]);
      v[2] = (short)f2bf(f[2 * c][2]);
      v[3] = (short)f2bf(f[2 * c][3]);
      v[4] = (short)f2bf(f[2 * c + 1][0]);
      v[5] = (short)f2bf(f[2 * c + 1][1]);
      v[6] = (short)f2bf(f[2 * c + 1][2]);
      v[7] = (short)f2bf(f[2 * c + 1][3]);
      *(short8*)((char*)As + swbase + (((schunk0 + c) ^ srxor) << 4)) = v;
    }
    // ---- stage B: already bf16
#pragma unroll
    for (int c = 0; c < 4; ++c) {
      short8 v = *(const short8*)(bptr + kt * BK + c * 8);
      *(short8*)((char*)Bs + swbase + (((schunk0 + c) ^ srxor) << 4)) = v;
    }
    __syncthreads();

#pragma unroll
    for (int ks = 0; ks < 2; ++ks) {
      short8 af[4], bf[4];
#pragma unroll
      for (int mi = 0; mi < 4; ++mi) {
        int r = wrow * 64 + mi * 16 + lc;
        af[mi] = *(const short8*)((const char*)As + r * 128 +
                                  ((((ks << 2) | l4) ^ (lc & 7)) << 4));
      }
#pragma unroll
      for (int ni = 0; ni < 4; ++ni) {
        int r = wcol * 64 + ni * 16 + lc;
        bf[ni] = *(const short8*)((const char*)Bs + r * 128 +
                                  ((((ks << 2) | l4) ^ (lc & 7)) << 4));
      }
#pragma unroll
      for (int mi = 0; mi < 4; ++mi)
#pragma unroll
        for (int ni = 0; ni < 4; ++ni)
          acc[mi][ni] = __builtin_amdgcn_mfma_f32_16x16x32_bf16(
              af[mi], bf[ni], acc[mi][ni], 0, 0, 0);
    }
    __syncthreads();
  }

  // ---- epilogue: g = acc + be + gdec; tanh; * Wv; reduce over 128 cols
  float sp[4][4];
#pragma unroll
  for (int mi = 0; mi < 4; ++mi) {
#pragma unroll
    for (int j = 0; j < 4; ++j) {
      float s = 0.f;
#pragma unroll
      for (int ni = 0; ni < 4; ++ni) {
        int c  = wcol * 64 + ni * 16 + lc;
        float g = acc[mi][ni][j] + bg[c];
        s += tanhf(g) * wvl[c];
      }
      // sum over the 16 lanes (lc) covering this row's 64 cols of the wave
#pragma unroll
      for (int off = 1; off < 16; off <<= 1) s += __shfl_xor(s, off);
      sp[mi][j] = s;
    }
  }
  if (lc == 0) {
#pragma unroll
    for (int mi = 0; mi < 4; ++mi)
#pragma unroll
      for (int j = 0; j < 4; ++j)
        sred[wcol][wrow * 64 + mi * 16 + l4 * 4 + j] = sp[mi][j];
  }
  __syncthreads();
  if (tid < BM)
    spart_g[(size_t)blockIdx.y * M_TOT + m0 + tid] = sred[0][tid] + sred[1][tid];
}

// ---------------- reduce partials + bv, softmax over S per b ----------------
__global__ void softmax_kernel(const float* __restrict__ spart,
                               const float* __restrict__ bv,
                               float* __restrict__ wout) {
  int b = blockIdx.x, tid = threadIdx.x;  // 256 threads
  int lane = tid & 63, wid = tid >> 6;
  __shared__ float red[4];
  float bv0 = bv[0];
  float v[4];
#pragma unroll
  for (int i = 0; i < 4; ++i) {
    int m = b * S_ + i * 256 + tid;
    float s = bv0;
#pragma unroll
    for (int nb = 0; nb < 8; ++nb) s += spart[(size_t)nb * M_TOT + m];
    v[i] = s;
  }
  float mx = fmaxf(fmaxf(v[0], v[1]), fmaxf(v[2], v[3]));
#pragma unroll
  for (int off = 1; off < 64; off <<= 1) mx = fmaxf(mx, __shfl_xor(mx, off));
  if (lane == 0) red[wid] = mx;
  __syncthreads();
  mx = fmaxf(fmaxf(red[0], red[1]), fmaxf(red[2], red[3]));
  __syncthreads();
  float e[4], sum = 0.f;
#pragma unroll
  for (int i = 0; i < 4; ++i) {
    e[i] = expf(v[i] - mx);
    sum += e[i];
  }
#pragma unroll
  for (int off = 1; off < 64; off <<= 1) sum += __shfl_xor(sum, off);
  if (lane == 0) red[wid] = sum;
  __syncthreads();
  sum = red[0] + red[1] + red[2] + red[3];
  float inv = 1.f / sum;
#pragma unroll
  for (int i = 0; i < 4; ++i)
    wout[b * S_ + i * 256 + tid] = e[i] * inv;
}

// ---------------- c_t partials: grid (2, 32, 8), 256 thr ----------------
__global__ void ct_partial_kernel(const float* __restrict__ ctx,
                                  const float* __restrict__ w,
                                  float* __restrict__ part) {
  int tid = threadIdx.x;
  int eh = blockIdx.x, b = blockIdx.y, sc = blockIdx.z;
  int e = eh * 1024 + tid * 4;
  const float* wp = w + b * S_ + sc * 128;
  const float* cp = ctx + (size_t)(b * S_ + sc * 128) * K_ + e;
  f32x4 acc = {0.f, 0.f, 0.f, 0.f};
#pragma unroll 4
  for (int s = 0; s < 128; ++s) {
    float ws_ = wp[s];
    f32x4 val = *(const f32x4*)(cp + (size_t)s * K_);
    acc += ws_ * val;
  }
  *(f32x4*)(part + (size_t)(sc * 32 + b) * K_ + e) = acc;
}

__global__ void ct_combine_kernel(const float* __restrict__ part,
                                  float* __restrict__ out) {
  int idx = blockIdx.x * 256 + threadIdx.x;  // 65536
  float s = 0.f;
#pragma unroll
  for (int p = 0; p < 8; ++p) s += part[(size_t)p * 65536 + idx];
  out[idx] = s;
}

extern "C" void kernel_launch(void* const* d_in, const int* in_sizes, int n_in,
                              void* d_out, int out_size, void* d_ws, size_t ws_size,
                              hipStream_t stream) {
  const float* ctx = (const float*)d_in[0];
  const float* dec = (const float*)d_in[1];
  const float* We  = (const float*)d_in[2];
  const float* be  = (const float*)d_in[3];
  const float* Wd  = (const float*)d_in[4];
  const float* bd  = (const float*)d_in[5];
  const float* Wv  = (const float*)d_in[6];
  const float* bv  = (const float*)d_in[7];
  float* out = (float*)d_out;
  char*  ws  = (char*)d_ws;

  unsigned short* WeT   = (unsigned short*)ws;                       // 4 MB
  float*          gdec  = (float*)(ws + (4u << 20));                 // 128 KB
  float*          spart = (float*)(ws + (4u << 20) + (128u << 10));  // 1 MB
  float*          ctpt  = (float*)ws;  // reuse WeT region after GEMM (2 MB)

  we_transpose_kernel<<<dim3(K_ / 32, H_ / 32), dim3(32, 8), 0, stream>>>(We, WeT);
  gdec_kernel<<<dim3(H_ / 256, B_), 256, 0, stream>>>(dec, Wd, bd, gdec);
  gemm_score_kernel<<<dim3(M_TOT / BM, H_ / BN), 256, 0, stream>>>(
      ctx, WeT, be, gdec, Wv, spart);
  softmax_kernel<<<B_, 256, 0, stream>>>(spart, bv, out + 65536);
  ct_partial_kernel<<<dim3(2, B_, 8), 256, 0, stream>>>(ctx, out + 65536, ctpt);
  ct_combine_kernel<<<256, 256, 0, stream>>>(ctpt, out);
}

// Round 2
// 408.400 us; speedup vs baseline: 1.2551x; 1.2551x over previous
//
#include <hip/hip_runtime.h>
#include <hip/hip_bf16.h>

typedef __attribute__((ext_vector_type(4))) float  f32x4;
typedef __attribute__((ext_vector_type(8))) short  short8;

#define H_    1024
#define K_    2048   // 2H
#define B_    32
#define S_    1024
#define M_TOT 32768  // B*S

#define BM 128
#define BN 128
#define BK 64

static __device__ __forceinline__ unsigned short f2bf(float f) {
  __hip_bfloat16 h = __float2bfloat16(f);
  return __builtin_bit_cast(unsigned short, h);
}
static __device__ __forceinline__ float bf2f(unsigned short u) {
  unsigned int x = ((unsigned int)u) << 16;
  return __builtin_bit_cast(float, x);
}

static __device__ __forceinline__ void gload_lds16(const void* g, void* l) {
  __builtin_amdgcn_global_load_lds(
      (const __attribute__((address_space(1))) unsigned int*)g,
      (__attribute__((address_space(3))) unsigned int*)l, 16, 0, 0);
}

// ---------------- prep: ctx fp32 [M][K] -> bf16 [M][K] ----------------
__global__ __launch_bounds__(256)
void ctx_convert_kernel(const float* __restrict__ ctx,
                        unsigned short* __restrict__ ctxb) {
  int idx = blockIdx.x * 256 + threadIdx.x;  // 524288 threads
#pragma unroll
  for (int j = 0; j < 16; ++j) {
    size_t e = ((size_t)j * 524288 + idx) * 8;
    f32x4 a = *(const f32x4*)(ctx + e);
    f32x4 b = *(const f32x4*)(ctx + e + 4);
    short8 v;
    v[0] = (short)f2bf(a[0]); v[1] = (short)f2bf(a[1]);
    v[2] = (short)f2bf(a[2]); v[3] = (short)f2bf(a[3]);
    v[4] = (short)f2bf(b[0]); v[5] = (short)f2bf(b[1]);
    v[6] = (short)f2bf(b[2]); v[7] = (short)f2bf(b[3]);
    *(short8*)(ctxb + e) = v;
  }
}

// ---------------- prep: We [K][H] fp32 -> WeT [H][K] bf16 ----------------
__global__ void we_transpose_kernel(const float* __restrict__ We,
                                    unsigned short* __restrict__ WeT) {
  __shared__ float tile[32][33];
  int k0 = blockIdx.x * 32;
  int n0 = blockIdx.y * 32;
  int tx = threadIdx.x, ty = threadIdx.y;  // block (32,8)
#pragma unroll
  for (int i = 0; i < 32; i += 8)
    tile[ty + i][tx] = We[(size_t)(k0 + ty + i) * H_ + n0 + tx];
  __syncthreads();
#pragma unroll
  for (int i = 0; i < 32; i += 8)
    WeT[(size_t)(n0 + ty + i) * K_ + k0 + tx] = f2bf(tile[tx][ty + i]);
}

// ---------------- gamma_dec[b][h] = bd[h] + dec[b,:] @ Wd[:,h] ----------------
__global__ void gdec_kernel(const float* __restrict__ dec,
                            const float* __restrict__ Wd,
                            const float* __restrict__ bd,
                            float* __restrict__ gdec) {
  int h = blockIdx.x * 256 + threadIdx.x;
  int b = blockIdx.y;
  const float* dp = dec + b * H_;
  float acc = bd[h];
#pragma unroll 8
  for (int k = 0; k < H_; ++k) acc += dp[k] * Wd[(size_t)k * H_ + h];
  gdec[b * H_ + h] = acc;
}

// ---------------- fused GEMM + tanh + Wv-reduce -> partial scores ----------
// m97 structure: global_load_lds width-16, linear LDS, 2-barrier K-loop.
// grid: 2048 linear blocks, XCD-swizzled: xcd = bid&7 owns m-tiles [x*32,x*32+32)
__global__ __launch_bounds__(256)
void gemm_score_kernel(const unsigned short* __restrict__ Abf,
                       const unsigned short* __restrict__ WeT,
                       const float* __restrict__ be,
                       const float* __restrict__ gdec,
                       const float* __restrict__ Wv,
                       float* __restrict__ spart_g) {
  __shared__ __align__(16) unsigned short As[BM * BK];  // linear [row][64]
  __shared__ __align__(16) unsigned short Bs[BN * BK];  // linear [n][64]
  __shared__ float bg[BN];
  __shared__ float wvl[BN];
  __shared__ float sred[2][BM];

  const int tid  = threadIdx.x;
  const int lane = tid & 63;
  const int wid  = tid >> 6;
  const int wrow = wid >> 1, wcol = wid & 1;
  const int lc = lane & 15, l4 = lane >> 4;

  // XCD-aware decode: bid%8 = XCD; XCD x gets m-tiles [x*32, x*32+32), n fastest
  const int bid = blockIdx.x;
  const int x   = bid & 7;
  const int c   = bid >> 3;
  const int mt  = x * 32 + (c >> 3);
  const int nt  = c & 7;
  const int m0  = mt * BM;
  const int n0  = nt * BN;
  const int b   = m0 >> 10;  // S=1024

  if (tid < BN) {
    bg[tid]  = be[n0 + tid] + gdec[b * H_ + n0 + tid];
    wvl[tid] = Wv[n0 + tid];
  }

  // staging: wave w, issue i covers LDS bytes [(w*4+i)*1024, +1024):
  //   lane l -> row (w*4+i)*8 + l/8, col (l%8)*8 (bf16)
  const int srow = wid * 32 + (lane >> 3) * 4;  // base row for issues via +8*i
  const int scol = (lane & 7) * 8;
  const unsigned short* aB = Abf + (size_t)(m0 + (wid * 32) + (lane >> 3)) * K_ + scol;
  const unsigned short* bB = WeT + (size_t)(n0 + (wid * 32) + (lane >> 3)) * K_ + scol;
  unsigned short* asB = As + (size_t)(wid * 4) * 512;  // wave-uniform bases
  unsigned short* bsB = Bs + (size_t)(wid * 4) * 512;
  (void)srow;

  f32x4 acc[4][4];
#pragma unroll
  for (int mi = 0; mi < 4; ++mi)
#pragma unroll
    for (int ni = 0; ni < 4; ++ni) {
      f32x4 z = {0.f, 0.f, 0.f, 0.f};
      acc[mi][ni] = z;
    }

  for (int kt = 0; kt < K_ / BK; ++kt) {
    const int ko = kt * BK;
#pragma unroll
    for (int i = 0; i < 4; ++i) {
      gload_lds16(aB + (size_t)i * 8 * K_ + ko, asB + i * 512);
      gload_lds16(bB + (size_t)i * 8 * K_ + ko, bsB + i * 512);
    }
    __syncthreads();  // compiler drains vmcnt(0) here

#pragma unroll
    for (int ks = 0; ks < 2; ++ks) {
      short8 af[4], bf[4];
#pragma unroll
      for (int mi = 0; mi < 4; ++mi) {
        int r = wrow * 64 + mi * 16 + lc;
        af[mi] = *(const short8*)((const char*)As + r * 128 + ks * 64 + l4 * 16);
      }
#pragma unroll
      for (int ni = 0; ni < 4; ++ni) {
        int r = wcol * 64 + ni * 16 + lc;
        bf[ni] = *(const short8*)((const char*)Bs + r * 128 + ks * 64 + l4 * 16);
      }
#pragma unroll
      for (int mi = 0; mi < 4; ++mi)
#pragma unroll
        for (int ni = 0; ni < 4; ++ni)
          acc[mi][ni] = __builtin_amdgcn_mfma_f32_16x16x32_bf16(
              af[mi], bf[ni], acc[mi][ni], 0, 0, 0);
    }
    __syncthreads();
  }

  // ---- epilogue: g = acc + be + gdec; tanh; * Wv; reduce over 128 cols
  float sp[4][4];
#pragma unroll
  for (int mi = 0; mi < 4; ++mi) {
#pragma unroll
    for (int j = 0; j < 4; ++j) {
      float s = 0.f;
#pragma unroll
      for (int ni = 0; ni < 4; ++ni) {
        int cC  = wcol * 64 + ni * 16 + lc;
        float g = acc[mi][ni][j] + bg[cC];
        s += tanhf(g) * wvl[cC];
      }
#pragma unroll
      for (int off = 1; off < 16; off <<= 1) s += __shfl_xor(s, off);
      sp[mi][j] = s;
    }
  }
  if (lc == 0) {
#pragma unroll
    for (int mi = 0; mi < 4; ++mi)
#pragma unroll
      for (int j = 0; j < 4; ++j)
        sred[wcol][wrow * 64 + mi * 16 + l4 * 4 + j] = sp[mi][j];
  }
  __syncthreads();
  if (tid < BM)
    spart_g[(size_t)nt * M_TOT + m0 + tid] = sred[0][tid] + sred[1][tid];
}

// ---------------- reduce partials + bv, softmax over S per b ----------------
__global__ void softmax_kernel(const float* __restrict__ spart,
                               const float* __restrict__ bv,
                               float* __restrict__ wout) {
  int b = blockIdx.x, tid = threadIdx.x;  // 256 threads
  int lane = tid & 63, wid = tid >> 6;
  __shared__ float red[4];
  float bv0 = bv[0];
  float v[4];
#pragma unroll
  for (int i = 0; i < 4; ++i) {
    int m = b * S_ + i * 256 + tid;
    float s = bv0;
#pragma unroll
    for (int nb = 0; nb < 8; ++nb) s += spart[(size_t)nb * M_TOT + m];
    v[i] = s;
  }
  float mx = fmaxf(fmaxf(v[0], v[1]), fmaxf(v[2], v[3]));
#pragma unroll
  for (int off = 1; off < 64; off <<= 1) mx = fmaxf(mx, __shfl_xor(mx, off));
  if (lane == 0) red[wid] = mx;
  __syncthreads();
  mx = fmaxf(fmaxf(red[0], red[1]), fmaxf(red[2], red[3]));
  __syncthreads();
  float e[4], sum = 0.f;
#pragma unroll
  for (int i = 0; i < 4; ++i) {
    e[i] = expf(v[i] - mx);
    sum += e[i];
  }
#pragma unroll
  for (int off = 1; off < 64; off <<= 1) sum += __shfl_xor(sum, off);
  if (lane == 0) red[wid] = sum;
  __syncthreads();
  sum = red[0] + red[1] + red[2] + red[3];
  float inv = 1.f / sum;
#pragma unroll
  for (int i = 0; i < 4; ++i)
    wout[b * S_ + i * 256 + tid] = e[i] * inv;
}

// ---------------- c_t partials from bf16 ctx: grid (32 b, 32 sc) ----------
__global__ __launch_bounds__(256)
void ct_partial_bf_kernel(const unsigned short* __restrict__ ctxb,
                          const float* __restrict__ w,
                          float* __restrict__ part) {
  int tid = threadIdx.x;
  int b = blockIdx.x, sc = blockIdx.y;
  int e0 = tid * 8;
  const float* wp = w + b * S_ + sc * 32;
  const unsigned short* cp = ctxb + (size_t)(b * S_ + sc * 32) * K_ + e0;
  float acc[8];
#pragma unroll
  for (int j = 0; j < 8; ++j) acc[j] = 0.f;
#pragma unroll 4
  for (int s = 0; s < 32; ++s) {
    float ws_ = wp[s];
    short8 v = *(const short8*)(cp + (size_t)s * K_);
#pragma unroll
    for (int j = 0; j < 8; ++j)
      acc[j] += ws_ * bf2f((unsigned short)v[j]);
  }
  float* dst = part + (size_t)sc * 65536 + (size_t)b * K_ + e0;
#pragma unroll
  for (int j = 0; j < 8; ++j) dst[j] = acc[j];
}

__global__ void ct_combine32_kernel(const float* __restrict__ part,
                                    float* __restrict__ out) {
  int idx = blockIdx.x * 256 + threadIdx.x;  // 65536
  float s = 0.f;
#pragma unroll
  for (int p = 0; p < 32; ++p) s += part[(size_t)p * 65536 + idx];
  out[idx] = s;
}

// ================= fallback path (R1, reg-staging, fp32 ct) =================
__global__ __launch_bounds__(256)
void gemm_score_fb_kernel(const float* __restrict__ ctx,
                          const unsigned short* __restrict__ WeT,
                          const float* __restrict__ be,
                          const float* __restrict__ gdec,
                          const float* __restrict__ Wv,
                          float* __restrict__ spart_g) {
  __shared__ __align__(16) unsigned short As[BM * BK];
  __shared__ __align__(16) unsigned short Bs[BN * BK];
  __shared__ float bg[BN];
  __shared__ float wvl[BN];
  __shared__ float sred[2][BM];

  const int tid  = threadIdx.x;
  const int lane = tid & 63;
  const int wid  = tid >> 6;
  const int wrow = wid >> 1, wcol = wid & 1;
  const int lc = lane & 15, l4 = lane >> 4;
  const int m0 = blockIdx.x * BM;
  const int n0 = blockIdx.y * BN;
  const int b  = m0 >> 10;

  if (tid < BN) {
    bg[tid]  = be[n0 + tid] + gdec[b * H_ + n0 + tid];
    wvl[tid] = Wv[n0 + tid];
  }
  const int srow  = tid >> 1;
  const int shalf = tid & 1;
  const float*          aptr = ctx + (size_t)(m0 + srow) * K_ + shalf * 32;
  const unsigned short* bptr = WeT + (size_t)(n0 + srow) * K_ + shalf * 32;
  const int swbase  = srow * 128;
  const int schunk0 = shalf * 4;
  const int srxor   = srow & 7;

  f32x4 acc[4][4];
#pragma unroll
  for (int mi = 0; mi < 4; ++mi)
#pragma unroll
    for (int ni = 0; ni < 4; ++ni) {
      f32x4 z = {0.f, 0.f, 0.f, 0.f};
      acc[mi][ni] = z;
    }
  for (int kt = 0; kt < K_ / BK; ++kt) {
    f32x4 f[8];
#pragma unroll
    for (int cc = 0; cc < 8; ++cc)
      f[cc] = *(const f32x4*)(aptr + kt * BK + cc * 4);
#pragma unroll
    for (int cc = 0; cc < 4; ++cc) {
      short8 v;
      v[0] = (short)f2bf(f[2 * cc][0]);
      v[1] = (short)f2bf(f[2 * cc][1]);
      v[2] = (short)f2bf(f[2 * cc][2]);
      v[3] = (short)f2bf(f[2 * cc][3]);
      v[4] = (short)f2bf(f[2 * cc + 1][0]);
      v[5] = (short)f2bf(f[2 * cc + 1][1]);
      v[6] = (short)f2bf(f[2 * cc + 1][2]);
      v[7] = (short)f2bf(f[2 * cc + 1][3]);
      *(short8*)((char*)As + swbase + (((schunk0 + cc) ^ srxor) << 4)) = v;
    }
#pragma unroll
    for (int cc = 0; cc < 4; ++cc) {
      short8 v = *(const short8*)(bptr + kt * BK + cc * 8);
      *(short8*)((char*)Bs + swbase + (((schunk0 + cc) ^ srxor) << 4)) = v;
    }
    __syncthreads();
#pragma unroll
    for (int ks = 0; ks < 2; ++ks) {
      short8 af[4], bf[4];
#pragma unroll
      for (int mi = 0; mi < 4; ++mi) {
        int r = wrow * 64 + mi * 16 + lc;
        af[mi] = *(const short8*)((const char*)As + r * 128 +
                                  ((((ks << 2) | l4) ^ (lc & 7)) << 4));
      }
#pragma unroll
      for (int ni = 0; ni < 4; ++ni) {
        int r = wcol * 64 + ni * 16 + lc;
        bf[ni] = *(const short8*)((const char*)Bs + r * 128 +
                                  ((((ks << 2) | l4) ^ (lc & 7)) << 4));
      }
#pragma unroll
      for (int mi = 0; mi < 4; ++mi)
#pragma unroll
        for (int ni = 0; ni < 4; ++ni)
          acc[mi][ni] = __builtin_amdgcn_mfma_f32_16x16x32_bf16(
              af[mi], bf[ni], acc[mi][ni], 0, 0, 0);
    }
    __syncthreads();
  }
  float sp[4][4];
#pragma unroll
  for (int mi = 0; mi < 4; ++mi) {
#pragma unroll
    for (int j = 0; j < 4; ++j) {
      float s = 0.f;
#pragma unroll
      for (int ni = 0; ni < 4; ++ni) {
        int cC  = wcol * 64 + ni * 16 + lc;
        float g = acc[mi][ni][j] + bg[cC];
        s += tanhf(g) * wvl[cC];
      }
#pragma unroll
      for (int off = 1; off < 16; off <<= 1) s += __shfl_xor(s, off);
      sp[mi][j] = s;
    }
  }
  if (lc == 0) {
#pragma unroll
    for (int mi = 0; mi < 4; ++mi)
#pragma unroll
      for (int j = 0; j < 4; ++j)
        sred[wcol][wrow * 64 + mi * 16 + l4 * 4 + j] = sp[mi][j];
  }
  __syncthreads();
  if (tid < BM)
    spart_g[(size_t)blockIdx.y * M_TOT + m0 + tid] = sred[0][tid] + sred[1][tid];
}

__global__ void ct_partial_fb_kernel(const float* __restrict__ ctx,
                                     const float* __restrict__ w,
                                     float* __restrict__ part) {
  int tid = threadIdx.x;
  int eh = blockIdx.x, b = blockIdx.y, sc = blockIdx.z;
  int e = eh * 1024 + tid * 4;
  const float* wp = w + b * S_ + sc * 128;
  const float* cp = ctx + (size_t)(b * S_ + sc * 128) * K_ + e;
  f32x4 acc = {0.f, 0.f, 0.f, 0.f};
#pragma unroll 4
  for (int s = 0; s < 128; ++s) {
    float ws_ = wp[s];
    f32x4 val = *(const f32x4*)(cp + (size_t)s * K_);
    acc += ws_ * val;
  }
  *(f32x4*)(part + (size_t)(sc * 32 + b) * K_ + e) = acc;
}

__global__ void ct_combine8_kernel(const float* __restrict__ part,
                                   float* __restrict__ out) {
  int idx = blockIdx.x * 256 + threadIdx.x;  // 65536
  float s = 0.f;
#pragma unroll
  for (int p = 0; p < 8; ++p) s += part[(size_t)p * 65536 + idx];
  out[idx] = s;
}

extern "C" void kernel_launch(void* const* d_in, const int* in_sizes, int n_in,
                              void* d_out, int out_size, void* d_ws, size_t ws_size,
                              hipStream_t stream) {
  const float* ctx = (const float*)d_in[0];
  const float* dec = (const float*)d_in[1];
  const float* We  = (const float*)d_in[2];
  const float* be  = (const float*)d_in[3];
  const float* Wd  = (const float*)d_in[4];
  const float* bd  = (const float*)d_in[5];
  const float* Wv  = (const float*)d_in[6];
  const float* bv  = (const float*)d_in[7];
  float* out = (float*)d_out;
  char*  ws  = (char*)d_ws;

  const size_t SZ_ABF  = (size_t)M_TOT * K_ * 2;      // 128 MB
  const size_t OFF_WET = SZ_ABF;                      // 4 MB
  const size_t OFF_GD  = OFF_WET + (size_t)H_ * K_ * 2;
  const size_t OFF_SP  = OFF_GD + (size_t)B_ * H_ * 4;
  const size_t OFF_CT  = OFF_SP + (size_t)8 * M_TOT * 4;
  const size_t NEED    = OFF_CT + (size_t)32 * 65536 * 4;

  if (ws_size >= NEED) {
    unsigned short* Abf  = (unsigned short*)ws;
    unsigned short* WeT  = (unsigned short*)(ws + OFF_WET);
    float*          gdec = (float*)(ws + OFF_GD);
    float*          spart= (float*)(ws + OFF_SP);
    float*          ctpt = (float*)(ws + OFF_CT);

    ctx_convert_kernel<<<2048, 256, 0, stream>>>(ctx, Abf);
    we_transpose_kernel<<<dim3(K_ / 32, H_ / 32), dim3(32, 8), 0, stream>>>(We, WeT);
    gdec_kernel<<<dim3(H_ / 256, B_), 256, 0, stream>>>(dec, Wd, bd, gdec);
    gemm_score_kernel<<<2048, 256, 0, stream>>>(Abf, WeT, be, gdec, Wv, spart);
    softmax_kernel<<<B_, 256, 0, stream>>>(spart, bv, out + 65536);
    ct_partial_bf_kernel<<<dim3(B_, 32), 256, 0, stream>>>(Abf, out + 65536, ctpt);
    ct_combine32_kernel<<<256, 256, 0, stream>>>(ctpt, out);
  } else {
    unsigned short* WeT   = (unsigned short*)ws;                       // 4 MB
    float*          gdec  = (float*)(ws + (4u << 20));                 // 128 KB
    float*          spart = (float*)(ws + (4u << 20) + (128u << 10));  // 1 MB
    float*          ctpt  = (float*)ws;  // reuse WeT region after GEMM

    we_transpose_kernel<<<dim3(K_ / 32, H_ / 32), dim3(32, 8), 0, stream>>>(We, WeT);
    gdec_kernel<<<dim3(H_ / 256, B_), 256, 0, stream>>>(dec, Wd, bd, gdec);
    gemm_score_fb_kernel<<<dim3(M_TOT / BM, H_ / BN), 256, 0, stream>>>(
        ctx, WeT, be, gdec, Wv, spart);
    softmax_kernel<<<B_, 256, 0, stream>>>(spart, bv, out + 65536);
    ct_partial_fb_kernel<<<dim3(2, B_, 8), 256, 0, stream>>>(ctx, out + 65536, ctpt);
    ct_combine8_kernel<<<256, 256, 0, stream>>>(ctpt, out);
  }
}

// Round 3
// 379.225 us; speedup vs baseline: 1.3517x; 1.0769x over previous
//
#include <hip/hip_runtime.h>
#include <hip/hip_bf16.h>

typedef __attribute__((ext_vector_type(4))) float  f32x4;
typedef __attribute__((ext_vector_type(8))) short  short8;

#define H_    1024
#define K_    2048   // 2H
#define B_    32
#define S_    1024
#define M_TOT 32768  // B*S

#define BM 128
#define BN 128
#define BK 64

static __device__ __forceinline__ unsigned short f2bf(float f) {
  __hip_bfloat16 h = __float2bfloat16(f);
  return __builtin_bit_cast(unsigned short, h);
}
static __device__ __forceinline__ float bf2f(unsigned short u) {
  unsigned int x = ((unsigned int)u) << 16;
  return __builtin_bit_cast(float, x);
}

static __device__ __forceinline__ void gload_lds16(const void* g, void* l) {
  __builtin_amdgcn_global_load_lds(
      (const __attribute__((address_space(1))) unsigned int*)g,
      (__attribute__((address_space(3))) unsigned int*)l, 16, 0, 0);
}

// ---------------- prep: ctx fp32 [M][K] -> bf16 [M][K] ----------------
__global__ __launch_bounds__(256)
void ctx_convert_kernel(const float* __restrict__ ctx,
                        unsigned short* __restrict__ ctxb) {
  int idx = blockIdx.x * 256 + threadIdx.x;  // 524288 threads
#pragma unroll
  for (int j = 0; j < 16; ++j) {
    size_t e = ((size_t)j * 524288 + idx) * 8;
    f32x4 a = *(const f32x4*)(ctx + e);
    f32x4 b = *(const f32x4*)(ctx + e + 4);
    short8 v;
    v[0] = (short)f2bf(a[0]); v[1] = (short)f2bf(a[1]);
    v[2] = (short)f2bf(a[2]); v[3] = (short)f2bf(a[3]);
    v[4] = (short)f2bf(b[0]); v[5] = (short)f2bf(b[1]);
    v[6] = (short)f2bf(b[2]); v[7] = (short)f2bf(b[3]);
    *(short8*)(ctxb + e) = v;
  }
}

// ---------------- prep: We [K][H] fp32 -> WeT [H][K] bf16 ----------------
__global__ void we_transpose_kernel(const float* __restrict__ We,
                                    unsigned short* __restrict__ WeT) {
  __shared__ float tile[32][33];
  int k0 = blockIdx.x * 32;
  int n0 = blockIdx.y * 32;
  int tx = threadIdx.x, ty = threadIdx.y;  // block (32,8)
#pragma unroll
  for (int i = 0; i < 32; i += 8)
    tile[ty + i][tx] = We[(size_t)(k0 + ty + i) * H_ + n0 + tx];
  __syncthreads();
#pragma unroll
  for (int i = 0; i < 32; i += 8)
    WeT[(size_t)(n0 + ty + i) * K_ + k0 + tx] = f2bf(tile[tx][ty + i]);
}

// ---------------- gamma_dec[b][h] = bd[h] + dec[b,:] @ Wd[:,h] ----------------
__global__ void gdec_kernel(const float* __restrict__ dec,
                            const float* __restrict__ Wd,
                            const float* __restrict__ bd,
                            float* __restrict__ gdec) {
  int h = blockIdx.x * 256 + threadIdx.x;
  int b = blockIdx.y;
  const float* dp = dec + b * H_;
  float acc = bd[h];
#pragma unroll 8
  for (int k = 0; k < H_; ++k) acc += dp[k] * Wd[(size_t)k * H_ + h];
  gdec[b * H_ + h] = acc;
}

// ---------------- fused GEMM + tanh + Wv-reduce -> partial scores ----------
// Double-buffered (T3-min): STAGE(next) -> COMPUTE(cur) -> barrier.
// LDS dest linear (global_load_lds), source pre-XOR-swizzled, read XOR-swizzled
// with the same involution (rule #21 / m201 pattern).
// grid: 2048 linear blocks, XCD-swizzled: bid&7 = XCD owns 32 m-tiles.
__global__ __launch_bounds__(256)
void gemm_score_kernel(const unsigned short* __restrict__ Abf,
                       const unsigned short* __restrict__ WeT,
                       const float* __restrict__ be,
                       const float* __restrict__ gdec,
                       const float* __restrict__ Wv,
                       float* __restrict__ spart_g) {
  __shared__ __align__(16) unsigned short As[2][BM * BK];  // 2 x 16 KB
  __shared__ __align__(16) unsigned short Bs[2][BN * BK];  // 2 x 16 KB
  __shared__ float bg[BN];
  __shared__ float wvl[BN];
  __shared__ float sred[2][BM];

  const int tid  = threadIdx.x;
  const int lane = tid & 63;
  const int wid  = tid >> 6;
  const int wrow = wid >> 1, wcol = wid & 1;
  const int lc = lane & 15, l4 = lane >> 4;

  // XCD-aware decode: bid%8 = XCD; XCD x gets m-tiles [x*32, x*32+32), n fastest
  const int bid = blockIdx.x;
  const int x   = bid & 7;
  const int c   = bid >> 3;
  const int mt  = x * 32 + (c >> 3);
  const int nt  = c & 7;
  const int m0  = mt * BM;
  const int n0  = nt * BN;
  const int b   = m0 >> 10;  // S=1024

  if (tid < BN) {
    bg[tid]  = be[n0 + tid] + gdec[b * H_ + n0 + tid];
    wvl[tid] = Wv[n0 + tid];
  }

  // staging geometry: wave w, issue i -> LDS bytes [(w*4+i)*1024, +1024) linear;
  // lane l -> row w*32 + i*8 + (l>>3); global chunk pre-swizzled by (l>>3)=row&7
  const int g8  = lane >> 3;                 // row&7 for all issues
  const int csw = ((lane & 7) ^ g8) * 8;     // swizzled source column (elements)
  const unsigned short* aB = Abf + (size_t)(m0 + wid * 32 + g8) * K_ + csw;
  const unsigned short* bB = WeT + (size_t)(n0 + wid * 32 + g8) * K_ + csw;

  f32x4 acc[4][4];
#pragma unroll
  for (int mi = 0; mi < 4; ++mi)
#pragma unroll
    for (int ni = 0; ni < 4; ++ni) {
      f32x4 z = {0.f, 0.f, 0.f, 0.f};
      acc[mi][ni] = z;
    }

  auto STAGE = [&](int bi, int ko) {
#pragma unroll
    for (int i = 0; i < 4; ++i) {
      gload_lds16(aB + (size_t)i * 8 * K_ + ko, &As[bi][(wid * 4 + i) * 512]);
      gload_lds16(bB + (size_t)i * 8 * K_ + ko, &Bs[bi][(wid * 4 + i) * 512]);
    }
  };
  auto COMPUTE = [&](int bi) {
#pragma unroll
    for (int ks = 0; ks < 2; ++ks) {
      short8 af[4], bf[4];
#pragma unroll
      for (int mi = 0; mi < 4; ++mi) {
        int r = wrow * 64 + mi * 16 + lc;
        af[mi] = *(const short8*)((const char*)&As[bi][0] + r * 128 +
                                  ((((ks << 2) | l4) ^ (lc & 7)) << 4));
      }
#pragma unroll
      for (int ni = 0; ni < 4; ++ni) {
        int r = wcol * 64 + ni * 16 + lc;
        bf[ni] = *(const short8*)((const char*)&Bs[bi][0] + r * 128 +
                                  ((((ks << 2) | l4) ^ (lc & 7)) << 4));
      }
#pragma unroll
      for (int mi = 0; mi < 4; ++mi)
#pragma unroll
        for (int ni = 0; ni < 4; ++ni)
          acc[mi][ni] = __builtin_amdgcn_mfma_f32_16x16x32_bf16(
              af[mi], bf[ni], acc[mi][ni], 0, 0, 0);
    }
  };

  int cur = 0;
  STAGE(0, 0);
  __syncthreads();
  for (int kt = 1; kt < K_ / BK; ++kt) {
    STAGE(cur ^ 1, kt * BK);   // prefetch next tile; flies under COMPUTE
    COMPUTE(cur);
    __syncthreads();           // drains vmcnt(0): next tile ready, cur reusable
    cur ^= 1;
  }
  COMPUTE(cur);

  // ---- epilogue: g = acc + be + gdec; tanh; * Wv; reduce over 128 cols
  float sp[4][4];
#pragma unroll
  for (int mi = 0; mi < 4; ++mi) {
#pragma unroll
    for (int j = 0; j < 4; ++j) {
      float s = 0.f;
#pragma unroll
      for (int ni = 0; ni < 4; ++ni) {
        int cC  = wcol * 64 + ni * 16 + lc;
        float g = acc[mi][ni][j] + bg[cC];
        s += tanhf(g) * wvl[cC];
      }
#pragma unroll
      for (int off = 1; off < 16; off <<= 1) s += __shfl_xor(s, off);
      sp[mi][j] = s;
    }
  }
  if (lc == 0) {
#pragma unroll
    for (int mi = 0; mi < 4; ++mi)
#pragma unroll
      for (int j = 0; j < 4; ++j)
        sred[wcol][wrow * 64 + mi * 16 + l4 * 4 + j] = sp[mi][j];
  }
  __syncthreads();
  if (tid < BM)
    spart_g[(size_t)nt * M_TOT + m0 + tid] = sred[0][tid] + sred[1][tid];
}

// ---------------- reduce partials + bv, softmax over S per b ----------------
__global__ void softmax_kernel(const float* __restrict__ spart,
                               const float* __restrict__ bv,
                               float* __restrict__ wout) {
  int b = blockIdx.x, tid = threadIdx.x;  // 256 threads
  int lane = tid & 63, wid = tid >> 6;
  __shared__ float red[4];
  float bv0 = bv[0];
  float v[4];
#pragma unroll
  for (int i = 0; i < 4; ++i) {
    int m = b * S_ + i * 256 + tid;
    float s = bv0;
#pragma unroll
    for (int nb = 0; nb < 8; ++nb) s += spart[(size_t)nb * M_TOT + m];
    v[i] = s;
  }
  float mx = fmaxf(fmaxf(v[0], v[1]), fmaxf(v[2], v[3]));
#pragma unroll
  for (int off = 1; off < 64; off <<= 1) mx = fmaxf(mx, __shfl_xor(mx, off));
  if (lane == 0) red[wid] = mx;
  __syncthreads();
  mx = fmaxf(fmaxf(red[0], red[1]), fmaxf(red[2], red[3]));
  __syncthreads();
  float e[4], sum = 0.f;
#pragma unroll
  for (int i = 0; i < 4; ++i) {
    e[i] = expf(v[i] - mx);
    sum += e[i];
  }
#pragma unroll
  for (int off = 1; off < 64; off <<= 1) sum += __shfl_xor(sum, off);
  if (lane == 0) red[wid] = sum;
  __syncthreads();
  sum = red[0] + red[1] + red[2] + red[3];
  float inv = 1.f / sum;
#pragma unroll
  for (int i = 0; i < 4; ++i)
    wout[b * S_ + i * 256 + tid] = e[i] * inv;
}

// ---------------- c_t partials from bf16 ctx: grid (32 b, 32 sc) ----------
__global__ __launch_bounds__(256)
void ct_partial_bf_kernel(const unsigned short* __restrict__ ctxb,
                          const float* __restrict__ w,
                          float* __restrict__ part) {
  int tid = threadIdx.x;
  int b = blockIdx.x, sc = blockIdx.y;
  int e0 = tid * 8;
  const float* wp = w + b * S_ + sc * 32;
  const unsigned short* cp = ctxb + (size_t)(b * S_ + sc * 32) * K_ + e0;
  float acc[8];
#pragma unroll
  for (int j = 0; j < 8; ++j) acc[j] = 0.f;
#pragma unroll 4
  for (int s = 0; s < 32; ++s) {
    float ws_ = wp[s];
    short8 v = *(const short8*)(cp + (size_t)s * K_);
#pragma unroll
    for (int j = 0; j < 8; ++j)
      acc[j] += ws_ * bf2f((unsigned short)v[j]);
  }
  float* dst = part + (size_t)sc * 65536 + (size_t)b * K_ + e0;
#pragma unroll
  for (int j = 0; j < 8; ++j) dst[j] = acc[j];
}

__global__ void ct_combine32_kernel(const float* __restrict__ part,
                                    float* __restrict__ out) {
  int idx = blockIdx.x * 256 + threadIdx.x;  // 65536
  float s = 0.f;
#pragma unroll
  for (int p = 0; p < 32; ++p) s += part[(size_t)p * 65536 + idx];
  out[idx] = s;
}

// ================= fallback path (R1, reg-staging, fp32 ct) =================
__global__ __launch_bounds__(256)
void gemm_score_fb_kernel(const float* __restrict__ ctx,
                          const unsigned short* __restrict__ WeT,
                          const float* __restrict__ be,
                          const float* __restrict__ gdec,
                          const float* __restrict__ Wv,
                          float* __restrict__ spart_g) {
  __shared__ __align__(16) unsigned short As[BM * BK];
  __shared__ __align__(16) unsigned short Bs[BN * BK];
  __shared__ float bg[BN];
  __shared__ float wvl[BN];
  __shared__ float sred[2][BM];

  const int tid  = threadIdx.x;
  const int lane = tid & 63;
  const int wid  = tid >> 6;
  const int wrow = wid >> 1, wcol = wid & 1;
  const int lc = lane & 15, l4 = lane >> 4;
  const int m0 = blockIdx.x * BM;
  const int n0 = blockIdx.y * BN;
  const int b  = m0 >> 10;

  if (tid < BN) {
    bg[tid]  = be[n0 + tid] + gdec[b * H_ + n0 + tid];
    wvl[tid] = Wv[n0 + tid];
  }
  const int srow  = tid >> 1;
  const int shalf = tid & 1;
  const float*          aptr = ctx + (size_t)(m0 + srow) * K_ + shalf * 32;
  const unsigned short* bptr = WeT + (size_t)(n0 + srow) * K_ + shalf * 32;
  const int swbase  = srow * 128;
  const int schunk0 = shalf * 4;
  const int srxor   = srow & 7;

  f32x4 acc[4][4];
#pragma unroll
  for (int mi = 0; mi < 4; ++mi)
#pragma unroll
    for (int ni = 0; ni < 4; ++ni) {
      f32x4 z = {0.f, 0.f, 0.f, 0.f};
      acc[mi][ni] = z;
    }
  for (int kt = 0; kt < K_ / BK; ++kt) {
    f32x4 f[8];
#pragma unroll
    for (int cc = 0; cc < 8; ++cc)
      f[cc] = *(const f32x4*)(aptr + kt * BK + cc * 4);
#pragma unroll
    for (int cc = 0; cc < 4; ++cc) {
      short8 v;
      v[0] = (short)f2bf(f[2 * cc][0]);
      v[1] = (short)f2bf(f[2 * cc][1]);
      v[2] = (short)f2bf(f[2 * cc][2]);
      v[3] = (short)f2bf(f[2 * cc][3]);
      v[4] = (short)f2bf(f[2 * cc + 1][0]);
      v[5] = (short)f2bf(f[2 * cc + 1][1]);
      v[6] = (short)f2bf(f[2 * cc + 1][2]);
      v[7] = (short)f2bf(f[2 * cc + 1][3]);
      *(short8*)((char*)As + swbase + (((schunk0 + cc) ^ srxor) << 4)) = v;
    }
#pragma unroll
    for (int cc = 0; cc < 4; ++cc) {
      short8 v = *(const short8*)(bptr + kt * BK + cc * 8);
      *(short8*)((char*)Bs + swbase + (((schunk0 + cc) ^ srxor) << 4)) = v;
    }
    __syncthreads();
#pragma unroll
    for (int ks = 0; ks < 2; ++ks) {
      short8 af[4], bf[4];
#pragma unroll
      for (int mi = 0; mi < 4; ++mi) {
        int r = wrow * 64 + mi * 16 + lc;
        af[mi] = *(const short8*)((const char*)As + r * 128 +
                                  ((((ks << 2) | l4) ^ (lc & 7)) << 4));
      }
#pragma unroll
      for (int ni = 0; ni < 4; ++ni) {
        int r = wcol * 64 + ni * 16 + lc;
        bf[ni] = *(const short8*)((const char*)Bs + r * 128 +
                                  ((((ks << 2) | l4) ^ (lc & 7)) << 4));
      }
#pragma unroll
      for (int mi = 0; mi < 4; ++mi)
#pragma unroll
        for (int ni = 0; ni < 4; ++ni)
          acc[mi][ni] = __builtin_amdgcn_mfma_f32_16x16x32_bf16(
              af[mi], bf[ni], acc[mi][ni], 0, 0, 0);
    }
    __syncthreads();
  }
  float sp[4][4];
#pragma unroll
  for (int mi = 0; mi < 4; ++mi) {
#pragma unroll
    for (int j = 0; j < 4; ++j) {
      float s = 0.f;
#pragma unroll
      for (int ni = 0; ni < 4; ++ni) {
        int cC  = wcol * 64 + ni * 16 + lc;
        float g = acc[mi][ni][j] + bg[cC];
        s += tanhf(g) * wvl[cC];
      }
#pragma unroll
      for (int off = 1; off < 16; off <<= 1) s += __shfl_xor(s, off);
      sp[mi][j] = s;
    }
  }
  if (lc == 0) {
#pragma unroll
    for (int mi = 0; mi < 4; ++mi)
#pragma unroll
      for (int j = 0; j < 4; ++j)
        sred[wcol][wrow * 64 + mi * 16 + l4 * 4 + j] = sp[mi][j];
  }
  __syncthreads();
  if (tid < BM)
    spart_g[(size_t)blockIdx.y * M_TOT + m0 + tid] = sred[0][tid] + sred[1][tid];
}

__global__ void ct_partial_fb_kernel(const float* __restrict__ ctx,
                                     const float* __restrict__ w,
                                     float* __restrict__ part) {
  int tid = threadIdx.x;
  int eh = blockIdx.x, b = blockIdx.y, sc = blockIdx.z;
  int e = eh * 1024 + tid * 4;
  const float* wp = w + b * S_ + sc * 128;
  const float* cp = ctx + (size_t)(b * S_ + sc * 128) * K_ + e;
  f32x4 acc = {0.f, 0.f, 0.f, 0.f};
#pragma unroll 4
  for (int s = 0; s < 128; ++s) {
    float ws_ = wp[s];
    f32x4 val = *(const f32x4*)(cp + (size_t)s * K_);
    acc += ws_ * val;
  }
  *(f32x4*)(part + (size_t)(sc * 32 + b) * K_ + e) = acc;
}

__global__ void ct_combine8_kernel(const float* __restrict__ part,
                                   float* __restrict__ out) {
  int idx = blockIdx.x * 256 + threadIdx.x;  // 65536
  float s = 0.f;
#pragma unroll
  for (int p = 0; p < 8; ++p) s += part[(size_t)p * 65536 + idx];
  out[idx] = s;
}

extern "C" void kernel_launch(void* const* d_in, const int* in_sizes, int n_in,
                              void* d_out, int out_size, void* d_ws, size_t ws_size,
                              hipStream_t stream) {
  const float* ctx = (const float*)d_in[0];
  const float* dec = (const float*)d_in[1];
  const float* We  = (const float*)d_in[2];
  const float* be  = (const float*)d_in[3];
  const float* Wd  = (const float*)d_in[4];
  const float* bd  = (const float*)d_in[5];
  const float* Wv  = (const float*)d_in[6];
  const float* bv  = (const float*)d_in[7];
  float* out = (float*)d_out;
  char*  ws  = (char*)d_ws;

  const size_t SZ_ABF  = (size_t)M_TOT * K_ * 2;      // 128 MB
  const size_t OFF_WET = SZ_ABF;                      // 4 MB
  const size_t OFF_GD  = OFF_WET + (size_t)H_ * K_ * 2;
  const size_t OFF_SP  = OFF_GD + (size_t)B_ * H_ * 4;
  const size_t OFF_CT  = OFF_SP + (size_t)8 * M_TOT * 4;
  const size_t NEED    = OFF_CT + (size_t)32 * 65536 * 4;

  if (ws_size >= NEED) {
    unsigned short* Abf  = (unsigned short*)ws;
    unsigned short* WeT  = (unsigned short*)(ws + OFF_WET);
    float*          gdec = (float*)(ws + OFF_GD);
    float*          spart= (float*)(ws + OFF_SP);
    float*          ctpt = (float*)(ws + OFF_CT);

    ctx_convert_kernel<<<2048, 256, 0, stream>>>(ctx, Abf);
    we_transpose_kernel<<<dim3(K_ / 32, H_ / 32), dim3(32, 8), 0, stream>>>(We, WeT);
    gdec_kernel<<<dim3(H_ / 256, B_), 256, 0, stream>>>(dec, Wd, bd, gdec);
    gemm_score_kernel<<<2048, 256, 0, stream>>>(Abf, WeT, be, gdec, Wv, spart);
    softmax_kernel<<<B_, 256, 0, stream>>>(spart, bv, out + 65536);
    ct_partial_bf_kernel<<<dim3(B_, 32), 256, 0, stream>>>(Abf, out + 65536, ctpt);
    ct_combine32_kernel<<<256, 256, 0, stream>>>(ctpt, out);
  } else {
    unsigned short* WeT   = (unsigned short*)ws;                       // 4 MB
    float*          gdec  = (float*)(ws + (4u << 20));                 // 128 KB
    float*          spart = (float*)(ws + (4u << 20) + (128u << 10));  // 1 MB
    float*          ctpt  = (float*)ws;  // reuse WeT region after GEMM

    we_transpose_kernel<<<dim3(K_ / 32, H_ / 32), dim3(32, 8), 0, stream>>>(We, WeT);
    gdec_kernel<<<dim3(H_ / 256, B_), 256, 0, stream>>>(dec, Wd, bd, gdec);
    gemm_score_fb_kernel<<<dim3(M_TOT / BM, H_ / BN), 256, 0, stream>>>(
        ctx, WeT, be, gdec, Wv, spart);
    softmax_kernel<<<B_, 256, 0, stream>>>(spart, bv, out + 65536);
    ct_partial_fb_kernel<<<dim3(2, B_, 8), 256, 0, stream>>>(ctx, out + 65536, ctpt);
    ct_combine8_kernel<<<256, 256, 0, stream>>>(ctpt, out);
  }
}

// Round 4
// 356.182 us; speedup vs baseline: 1.4391x; 1.0647x over previous
//
#include <hip/hip_runtime.h>
#include <hip/hip_bf16.h>

typedef __attribute__((ext_vector_type(4))) float  f32x4;
typedef __attribute__((ext_vector_type(8))) short  short8;

#define H_    1024
#define K_    2048   // 2H
#define B_    32
#define S_    1024
#define M_TOT 32768  // B*S

#define BM 128
#define BN 128
#define BK 64

static __device__ __forceinline__ unsigned short f2bf(float f) {
  __hip_bfloat16 h = __float2bfloat16(f);
  return __builtin_bit_cast(unsigned short, h);
}
static __device__ __forceinline__ float bf2f(unsigned short u) {
  unsigned int x = ((unsigned int)u) << 16;
  return __builtin_bit_cast(float, x);
}

// branchless tanh: 1 - 2/(e^{2x}+1); exp2-based, correct at +/-inf, ~1e-6 err
static __device__ __forceinline__ float fast_tanh(float x) {
  float e = __builtin_amdgcn_exp2f(x * 2.88539008177792681f);  // 2*log2(e)
  return 1.0f - 2.0f * __builtin_amdgcn_rcpf(e + 1.0f);
}

static __device__ __forceinline__ void gload_lds16(const void* g, void* l) {
  __builtin_amdgcn_global_load_lds(
      (const __attribute__((address_space(1))) unsigned int*)g,
      (__attribute__((address_space(3))) unsigned int*)l, 16, 0, 0);
}

// ---------------- prep: ctx fp32 [M][K] -> bf16 [M][K] ----------------
__global__ __launch_bounds__(256)
void ctx_convert_kernel(const float* __restrict__ ctx,
                        unsigned short* __restrict__ ctxb) {
  int idx = blockIdx.x * 256 + threadIdx.x;  // 524288 threads
#pragma unroll
  for (int j = 0; j < 16; ++j) {
    size_t e = ((size_t)j * 524288 + idx) * 8;
    f32x4 a = *(const f32x4*)(ctx + e);
    f32x4 b = *(const f32x4*)(ctx + e + 4);
    short8 v;
    v[0] = (short)f2bf(a[0]); v[1] = (short)f2bf(a[1]);
    v[2] = (short)f2bf(a[2]); v[3] = (short)f2bf(a[3]);
    v[4] = (short)f2bf(b[0]); v[5] = (short)f2bf(b[1]);
    v[6] = (short)f2bf(b[2]); v[7] = (short)f2bf(b[3]);
    *(short8*)(ctxb + e) = v;
  }
}

// ---------------- prep: We [K][H] fp32 -> WeT [H][K] bf16 ----------------
__global__ void we_transpose_kernel(const float* __restrict__ We,
                                    unsigned short* __restrict__ WeT) {
  __shared__ float tile[32][33];
  int k0 = blockIdx.x * 32;
  int n0 = blockIdx.y * 32;
  int tx = threadIdx.x, ty = threadIdx.y;  // block (32,8)
#pragma unroll
  for (int i = 0; i < 32; i += 8)
    tile[ty + i][tx] = We[(size_t)(k0 + ty + i) * H_ + n0 + tx];
  __syncthreads();
#pragma unroll
  for (int i = 0; i < 32; i += 8)
    WeT[(size_t)(n0 + ty + i) * K_ + k0 + tx] = f2bf(tile[tx][ty + i]);
}

// ---------------- gamma_dec[b][h] = bd[h] + dec[b,:] @ Wd[:,h] ----------------
__global__ void gdec_kernel(const float* __restrict__ dec,
                            const float* __restrict__ Wd,
                            const float* __restrict__ bd,
                            float* __restrict__ gdec) {
  int h = blockIdx.x * 256 + threadIdx.x;
  int b = blockIdx.y;
  const float* dp = dec + b * H_;
  float acc = bd[h];
#pragma unroll 8
  for (int k = 0; k < H_; ++k) acc += dp[k] * Wd[(size_t)k * H_ + h];
  gdec[b * H_ + h] = acc;
}

// ---------------- fused GEMM + tanh + Wv-reduce -> partial scores ----------
// Double-buffered (T3-min): STAGE(next) -> COMPUTE(cur) -> barrier.
// LDS dest linear (global_load_lds), source pre-XOR-swizzled, read XOR-swizzled
// with the same involution (rule #21 / m201 pattern).
// grid: 2048 linear blocks, XCD-swizzled: bid&7 = XCD owns 32 m-tiles.
__global__ __launch_bounds__(256)
void gemm_score_kernel(const unsigned short* __restrict__ Abf,
                       const unsigned short* __restrict__ WeT,
                       const float* __restrict__ be,
                       const float* __restrict__ gdec,
                       const float* __restrict__ Wv,
                       float* __restrict__ spart_g) {
  __shared__ __align__(16) unsigned short As[2][BM * BK];  // 2 x 16 KB
  __shared__ __align__(16) unsigned short Bs[2][BN * BK];  // 2 x 16 KB
  __shared__ float bg[BN];
  __shared__ float wvl[BN];
  __shared__ float sred[2][BM];

  const int tid  = threadIdx.x;
  const int lane = tid & 63;
  const int wid  = tid >> 6;
  const int wrow = wid >> 1, wcol = wid & 1;
  const int lc = lane & 15, l4 = lane >> 4;

  // XCD-aware decode: bid%8 = XCD; XCD x gets m-tiles [x*32, x*32+32), n fastest
  const int bid = blockIdx.x;
  const int x   = bid & 7;
  const int c   = bid >> 3;
  const int mt  = x * 32 + (c >> 3);
  const int nt  = c & 7;
  const int m0  = mt * BM;
  const int n0  = nt * BN;
  const int b   = m0 >> 10;  // S=1024

  if (tid < BN) {
    bg[tid]  = be[n0 + tid] + gdec[b * H_ + n0 + tid];
    wvl[tid] = Wv[n0 + tid];
  }

  // staging geometry: wave w, issue i -> LDS bytes [(w*4+i)*1024, +1024) linear;
  // lane l -> row w*32 + i*8 + (l>>3); global chunk pre-swizzled by (l>>3)=row&7
  const int g8  = lane >> 3;                 // row&7 for all issues
  const int csw = ((lane & 7) ^ g8) * 8;     // swizzled source column (elements)
  const unsigned short* aB = Abf + (size_t)(m0 + wid * 32 + g8) * K_ + csw;
  const unsigned short* bB = WeT + (size_t)(n0 + wid * 32 + g8) * K_ + csw;

  f32x4 acc[4][4];
#pragma unroll
  for (int mi = 0; mi < 4; ++mi)
#pragma unroll
    for (int ni = 0; ni < 4; ++ni) {
      f32x4 z = {0.f, 0.f, 0.f, 0.f};
      acc[mi][ni] = z;
    }

  auto STAGE = [&](int bi, int ko) {
#pragma unroll
    for (int i = 0; i < 4; ++i) {
      gload_lds16(aB + (size_t)i * 8 * K_ + ko, &As[bi][(wid * 4 + i) * 512]);
      gload_lds16(bB + (size_t)i * 8 * K_ + ko, &Bs[bi][(wid * 4 + i) * 512]);
    }
  };
  auto COMPUTE = [&](int bi) {
#pragma unroll
    for (int ks = 0; ks < 2; ++ks) {
      short8 af[4], bf[4];
#pragma unroll
      for (int mi = 0; mi < 4; ++mi) {
        int r = wrow * 64 + mi * 16 + lc;
        af[mi] = *(const short8*)((const char*)&As[bi][0] + r * 128 +
                                  ((((ks << 2) | l4) ^ (lc & 7)) << 4));
      }
#pragma unroll
      for (int ni = 0; ni < 4; ++ni) {
        int r = wcol * 64 + ni * 16 + lc;
        bf[ni] = *(const short8*)((const char*)&Bs[bi][0] + r * 128 +
                                  ((((ks << 2) | l4) ^ (lc & 7)) << 4));
      }
#pragma unroll
      for (int mi = 0; mi < 4; ++mi)
#pragma unroll
        for (int ni = 0; ni < 4; ++ni)
          acc[mi][ni] = __builtin_amdgcn_mfma_f32_16x16x32_bf16(
              af[mi], bf[ni], acc[mi][ni], 0, 0, 0);
    }
  };

  int cur = 0;
  STAGE(0, 0);
  __syncthreads();
  for (int kt = 1; kt < K_ / BK; ++kt) {
    STAGE(cur ^ 1, kt * BK);   // prefetch next tile; flies under COMPUTE
    COMPUTE(cur);
    __syncthreads();           // drains vmcnt(0): next tile ready, cur reusable
    cur ^= 1;
  }
  COMPUTE(cur);

  // ---- epilogue: g = acc + be + gdec; tanh; * Wv; reduce over 128 cols
  float sp[4][4];
#pragma unroll
  for (int mi = 0; mi < 4; ++mi) {
#pragma unroll
    for (int j = 0; j < 4; ++j) {
      float s = 0.f;
#pragma unroll
      for (int ni = 0; ni < 4; ++ni) {
        int cC  = wcol * 64 + ni * 16 + lc;
        float g = acc[mi][ni][j] + bg[cC];
        s += fast_tanh(g) * wvl[cC];
      }
#pragma unroll
      for (int off = 1; off < 16; off <<= 1) s += __shfl_xor(s, off);
      sp[mi][j] = s;
    }
  }
  if (lc == 0) {
#pragma unroll
    for (int mi = 0; mi < 4; ++mi)
#pragma unroll
      for (int j = 0; j < 4; ++j)
        sred[wcol][wrow * 64 + mi * 16 + l4 * 4 + j] = sp[mi][j];
  }
  __syncthreads();
  if (tid < BM)
    spart_g[(size_t)nt * M_TOT + m0 + tid] = sred[0][tid] + sred[1][tid];
}

// ---------------- reduce partials + bv, softmax over S per b ----------------
__global__ void softmax_kernel(const float* __restrict__ spart,
                               const float* __restrict__ bv,
                               float* __restrict__ wout) {
  int b = blockIdx.x, tid = threadIdx.x;  // 256 threads
  int lane = tid & 63, wid = tid >> 6;
  __shared__ float red[4];
  float bv0 = bv[0];
  float v[4];
#pragma unroll
  for (int i = 0; i < 4; ++i) {
    int m = b * S_ + i * 256 + tid;
    float s = bv0;
#pragma unroll
    for (int nb = 0; nb < 8; ++nb) s += spart[(size_t)nb * M_TOT + m];
    v[i] = s;
  }
  float mx = fmaxf(fmaxf(v[0], v[1]), fmaxf(v[2], v[3]));
#pragma unroll
  for (int off = 1; off < 64; off <<= 1) mx = fmaxf(mx, __shfl_xor(mx, off));
  if (lane == 0) red[wid] = mx;
  __syncthreads();
  mx = fmaxf(fmaxf(red[0], red[1]), fmaxf(red[2], red[3]));
  __syncthreads();
  float e[4], sum = 0.f;
#pragma unroll
  for (int i = 0; i < 4; ++i) {
    e[i] = expf(v[i] - mx);
    sum += e[i];
  }
#pragma unroll
  for (int off = 1; off < 64; off <<= 1) sum += __shfl_xor(sum, off);
  if (lane == 0) red[wid] = sum;
  __syncthreads();
  sum = red[0] + red[1] + red[2] + red[3];
  float inv = 1.f / sum;
#pragma unroll
  for (int i = 0; i < 4; ++i)
    wout[b * S_ + i * 256 + tid] = e[i] * inv;
}

// ---------------- c_t partials from bf16 ctx: grid (32 b, 32 sc) ----------
__global__ __launch_bounds__(256)
void ct_partial_bf_kernel(const unsigned short* __restrict__ ctxb,
                          const float* __restrict__ w,
                          float* __restrict__ part) {
  int tid = threadIdx.x;
  int b = blockIdx.x, sc = blockIdx.y;
  int e0 = tid * 8;
  const float* wp = w + b * S_ + sc * 32;
  const unsigned short* cp = ctxb + (size_t)(b * S_ + sc * 32) * K_ + e0;
  float acc[8];
#pragma unroll
  for (int j = 0; j < 8; ++j) acc[j] = 0.f;
#pragma unroll 4
  for (int s = 0; s < 32; ++s) {
    float ws_ = wp[s];
    short8 v = *(const short8*)(cp + (size_t)s * K_);
#pragma unroll
    for (int j = 0; j < 8; ++j)
      acc[j] += ws_ * bf2f((unsigned short)v[j]);
  }
  float* dst = part + (size_t)sc * 65536 + (size_t)b * K_ + e0;
#pragma unroll
  for (int j = 0; j < 8; ++j) dst[j] = acc[j];
}

__global__ void ct_combine32_kernel(const float* __restrict__ part,
                                    float* __restrict__ out) {
  int idx = blockIdx.x * 256 + threadIdx.x;  // 65536
  float s = 0.f;
#pragma unroll
  for (int p = 0; p < 32; ++p) s += part[(size_t)p * 65536 + idx];
  out[idx] = s;
}

// ================= fallback path (R1, reg-staging, fp32 ct) =================
__global__ __launch_bounds__(256)
void gemm_score_fb_kernel(const float* __restrict__ ctx,
                          const unsigned short* __restrict__ WeT,
                          const float* __restrict__ be,
                          const float* __restrict__ gdec,
                          const float* __restrict__ Wv,
                          float* __restrict__ spart_g) {
  __shared__ __align__(16) unsigned short As[BM * BK];
  __shared__ __align__(16) unsigned short Bs[BN * BK];
  __shared__ float bg[BN];
  __shared__ float wvl[BN];
  __shared__ float sred[2][BM];

  const int tid  = threadIdx.x;
  const int lane = tid & 63;
  const int wid  = tid >> 6;
  const int wrow = wid >> 1, wcol = wid & 1;
  const int lc = lane & 15, l4 = lane >> 4;
  const int m0 = blockIdx.x * BM;
  const int n0 = blockIdx.y * BN;
  const int b  = m0 >> 10;

  if (tid < BN) {
    bg[tid]  = be[n0 + tid] + gdec[b * H_ + n0 + tid];
    wvl[tid] = Wv[n0 + tid];
  }
  const int srow  = tid >> 1;
  const int shalf = tid & 1;
  const float*          aptr = ctx + (size_t)(m0 + srow) * K_ + shalf * 32;
  const unsigned short* bptr = WeT + (size_t)(n0 + srow) * K_ + shalf * 32;
  const int swbase  = srow * 128;
  const int schunk0 = shalf * 4;
  const int srxor   = srow & 7;

  f32x4 acc[4][4];
#pragma unroll
  for (int mi = 0; mi < 4; ++mi)
#pragma unroll
    for (int ni = 0; ni < 4; ++ni) {
      f32x4 z = {0.f, 0.f, 0.f, 0.f};
      acc[mi][ni] = z;
    }
  for (int kt = 0; kt < K_ / BK; ++kt) {
    f32x4 f[8];
#pragma unroll
    for (int cc = 0; cc < 8; ++cc)
      f[cc] = *(const f32x4*)(aptr + kt * BK + cc * 4);
#pragma unroll
    for (int cc = 0; cc < 4; ++cc) {
      short8 v;
      v[0] = (short)f2bf(f[2 * cc][0]);
      v[1] = (short)f2bf(f[2 * cc][1]);
      v[2] = (short)f2bf(f[2 * cc][2]);
      v[3] = (short)f2bf(f[2 * cc][3]);
      v[4] = (short)f2bf(f[2 * cc + 1][0]);
      v[5] = (short)f2bf(f[2 * cc + 1][1]);
      v[6] = (short)f2bf(f[2 * cc + 1][2]);
      v[7] = (short)f2bf(f[2 * cc + 1][3]);
      *(short8*)((char*)As + swbase + (((schunk0 + cc) ^ srxor) << 4)) = v;
    }
#pragma unroll
    for (int cc = 0; cc < 4; ++cc) {
      short8 v = *(const short8*)(bptr + kt * BK + cc * 8);
      *(short8*)((char*)Bs + swbase + (((schunk0 + cc) ^ srxor) << 4)) = v;
    }
    __syncthreads();
#pragma unroll
    for (int ks = 0; ks < 2; ++ks) {
      short8 af[4], bf[4];
#pragma unroll
      for (int mi = 0; mi < 4; ++mi) {
        int r = wrow * 64 + mi * 16 + lc;
        af[mi] = *(const short8*)((const char*)As + r * 128 +
                                  ((((ks << 2) | l4) ^ (lc & 7)) << 4));
      }
#pragma unroll
      for (int ni = 0; ni < 4; ++ni) {
        int r = wcol * 64 + ni * 16 + lc;
        bf[ni] = *(const short8*)((const char*)Bs + r * 128 +
                                  ((((ks << 2) | l4) ^ (lc & 7)) << 4));
      }
#pragma unroll
      for (int mi = 0; mi < 4; ++mi)
#pragma unroll
        for (int ni = 0; ni < 4; ++ni)
          acc[mi][ni] = __builtin_amdgcn_mfma_f32_16x16x32_bf16(
              af[mi], bf[ni], acc[mi][ni], 0, 0, 0);
    }
    __syncthreads();
  }
  float sp[4][4];
#pragma unroll
  for (int mi = 0; mi < 4; ++mi) {
#pragma unroll
    for (int j = 0; j < 4; ++j) {
      float s = 0.f;
#pragma unroll
      for (int ni = 0; ni < 4; ++ni) {
        int cC  = wcol * 64 + ni * 16 + lc;
        float g = acc[mi][ni][j] + bg[cC];
        s += fast_tanh(g) * wvl[cC];
      }
#pragma unroll
      for (int off = 1; off < 16; off <<= 1) s += __shfl_xor(s, off);
      sp[mi][j] = s;
    }
  }
  if (lc == 0) {
#pragma unroll
    for (int mi = 0; mi < 4; ++mi)
#pragma unroll
      for (int j = 0; j < 4; ++j)
        sred[wcol][wrow * 64 + mi * 16 + l4 * 4 + j] = sp[mi][j];
  }
  __syncthreads();
  if (tid < BM)
    spart_g[(size_t)blockIdx.y * M_TOT + m0 + tid] = sred[0][tid] + sred[1][tid];
}

__global__ void ct_partial_fb_kernel(const float* __restrict__ ctx,
                                     const float* __restrict__ w,
                                     float* __restrict__ part) {
  int tid = threadIdx.x;
  int eh = blockIdx.x, b = blockIdx.y, sc = blockIdx.z;
  int e = eh * 1024 + tid * 4;
  const float* wp = w + b * S_ + sc * 128;
  const float* cp = ctx + (size_t)(b * S_ + sc * 128) * K_ + e;
  f32x4 acc = {0.f, 0.f, 0.f, 0.f};
#pragma unroll 4
  for (int s = 0; s < 128; ++s) {
    float ws_ = wp[s];
    f32x4 val = *(const f32x4*)(cp + (size_t)s * K_);
    acc += ws_ * val;
  }
  *(f32x4*)(part + (size_t)(sc * 32 + b) * K_ + e) = acc;
}

__global__ void ct_combine8_kernel(const float* __restrict__ part,
                                   float* __restrict__ out) {
  int idx = blockIdx.x * 256 + threadIdx.x;  // 65536
  float s = 0.f;
#pragma unroll
  for (int p = 0; p < 8; ++p) s += part[(size_t)p * 65536 + idx];
  out[idx] = s;
}

extern "C" void kernel_launch(void* const* d_in, const int* in_sizes, int n_in,
                              void* d_out, int out_size, void* d_ws, size_t ws_size,
                              hipStream_t stream) {
  const float* ctx = (const float*)d_in[0];
  const float* dec = (const float*)d_in[1];
  const float* We  = (const float*)d_in[2];
  const float* be  = (const float*)d_in[3];
  const float* Wd  = (const float*)d_in[4];
  const float* bd  = (const float*)d_in[5];
  const float* Wv  = (const float*)d_in[6];
  const float* bv  = (const float*)d_in[7];
  float* out = (float*)d_out;
  char*  ws  = (char*)d_ws;

  const size_t SZ_ABF  = (size_t)M_TOT * K_ * 2;      // 128 MB
  const size_t OFF_WET = SZ_ABF;                      // 4 MB
  const size_t OFF_GD  = OFF_WET + (size_t)H_ * K_ * 2;
  const size_t OFF_SP  = OFF_GD + (size_t)B_ * H_ * 4;
  const size_t OFF_CT  = OFF_SP + (size_t)8 * M_TOT * 4;
  const size_t NEED    = OFF_CT + (size_t)32 * 65536 * 4;

  if (ws_size >= NEED) {
    unsigned short* Abf  = (unsigned short*)ws;
    unsigned short* WeT  = (unsigned short*)(ws + OFF_WET);
    float*          gdec = (float*)(ws + OFF_GD);
    float*          spart= (float*)(ws + OFF_SP);
    float*          ctpt = (float*)(ws + OFF_CT);

    ctx_convert_kernel<<<2048, 256, 0, stream>>>(ctx, Abf);
    we_transpose_kernel<<<dim3(K_ / 32, H_ / 32), dim3(32, 8), 0, stream>>>(We, WeT);
    gdec_kernel<<<dim3(H_ / 256, B_), 256, 0, stream>>>(dec, Wd, bd, gdec);
    gemm_score_kernel<<<2048, 256, 0, stream>>>(Abf, WeT, be, gdec, Wv, spart);
    softmax_kernel<<<B_, 256, 0, stream>>>(spart, bv, out + 65536);
    ct_partial_bf_kernel<<<dim3(B_, 32), 256, 0, stream>>>(Abf, out + 65536, ctpt);
    ct_combine32_kernel<<<256, 256, 0, stream>>>(ctpt, out);
  } else {
    unsigned short* WeT   = (unsigned short*)ws;                       // 4 MB
    float*          gdec  = (float*)(ws + (4u << 20));                 // 128 KB
    float*          spart = (float*)(ws + (4u << 20) + (128u << 10));  // 1 MB
    float*          ctpt  = (float*)ws;  // reuse WeT region after GEMM

    we_transpose_kernel<<<dim3(K_ / 32, H_ / 32), dim3(32, 8), 0, stream>>>(We, WeT);
    gdec_kernel<<<dim3(H_ / 256, B_), 256, 0, stream>>>(dec, Wd, bd, gdec);
    gemm_score_fb_kernel<<<dim3(M_TOT / BM, H_ / BN), 256, 0, stream>>>(
        ctx, WeT, be, gdec, Wv, spart);
    softmax_kernel<<<B_, 256, 0, stream>>>(spart, bv, out + 65536);
    ct_partial_fb_kernel<<<dim3(2, B_, 8), 256, 0, stream>>>(ctx, out + 65536, ctpt);
    ct_combine8_kernel<<<256, 256, 0, stream>>>(ctpt, out);
  }
}